// Round 1
// baseline (337.244 us; speedup 1.0000x reference)
//
#include <hip/hip_runtime.h>

// HopfieldTSP: reference iterates x = sign(w @ x) 1000 times, with
// w = -adj off-diagonal, w_ii = 2*rowsum_i.
//
// Math: for any x in {±1}^n, (w@x)_i = (2*rowsum_i + adj_ii)*x_i - (adj@x)_i,
// and since adj >= 0, |(adj@x)_i| <= rowsum_i < 2*rowsum_i. So every ±1
// vector is a fixed point: sign(w@x) = x. Hence x_1000 = x_1 = sign(w @ x0).
// The entire problem is ONE fused matvec + rowsum pass (256 MiB HBM read).
//
// This version vs. the 352 µs predecessor:
//  - x staged in LDS once per block (kills ~256 MB of device-wide x re-fetch
//    and removes x from the vmcnt queue entirely)
//  - adj read via nontemporal loads (zero-reuse stream; don't thrash caches)
//  - 4 independent accumulator chains (no serial-FMA stall; compiler can't
//    reassociate FP adds itself)
//  - 512-thread blocks, 1 row/wave, grid=1024: 4 blocks/CU = 32 waves/CU
//    with 32 KB LDS/block, each wave holding 4 KB of adj in flight.

#define N_CITIES 8192
#define NV4      (N_CITIES / 4)          // 2048 float4 per row
#define THREADS  512
#define ROWS_PER_BLOCK (THREADS / 64)    // 8 waves -> 8 rows

typedef float fv4 __attribute__((ext_vector_type(4)));

__global__ __launch_bounds__(THREADS, 8) void
hopfield_onestep_kernel(const float* __restrict__ adj,
                        const float* __restrict__ x,
                        float* __restrict__ out) {
    __shared__ fv4 xs[NV4];              // 32 KB: the whole x vector

    const int tid  = threadIdx.x;
    const int wave = tid >> 6;
    const int lane = tid & 63;

    // Cooperative stage of x into LDS (reused by all 8 rows in this block).
    const fv4* __restrict__ xg4 = (const fv4*)x;
    #pragma unroll
    for (int i = tid; i < NV4; i += THREADS) xs[i] = xg4[i];
    __syncthreads();

    const int row = blockIdx.x * ROWS_PER_BLOCK + wave;
    const fv4* __restrict__ arow = (const fv4*)(adj + (size_t)row * N_CITIES);

    // 2048 float4 / 64 lanes = 32 per lane; manual unroll x4 -> 8 iterations,
    // 4 independent accumulator chains for dot and rowsum.
    float d0 = 0.f, d1 = 0.f, d2 = 0.f, d3 = 0.f;
    float r0 = 0.f, r1 = 0.f, r2 = 0.f, r3 = 0.f;

    for (int c = lane; c < NV4; c += 256) {
        fv4 a0 = __builtin_nontemporal_load(arow + c);
        fv4 a1 = __builtin_nontemporal_load(arow + c + 64);
        fv4 a2 = __builtin_nontemporal_load(arow + c + 128);
        fv4 a3 = __builtin_nontemporal_load(arow + c + 192);
        fv4 x0 = xs[c];
        fv4 x1 = xs[c + 64];
        fv4 x2 = xs[c + 128];
        fv4 x3 = xs[c + 192];

        d0 += a0.x * x0.x + a0.y * x0.y + a0.z * x0.z + a0.w * x0.w;
        r0 += a0.x + a0.y + a0.z + a0.w;
        d1 += a1.x * x1.x + a1.y * x1.y + a1.z * x1.z + a1.w * x1.w;
        r1 += a1.x + a1.y + a1.z + a1.w;
        d2 += a2.x * x2.x + a2.y * x2.y + a2.z * x2.z + a2.w * x2.w;
        r2 += a2.x + a2.y + a2.z + a2.w;
        d3 += a3.x * x3.x + a3.y * x3.y + a3.z * x3.z + a3.w * x3.w;
        r3 += a3.x + a3.y + a3.z + a3.w;
    }

    float dot  = (d0 + d1) + (d2 + d3);
    float rsum = (r0 + r1) + (r2 + r3);

    // wave64 butterfly reduction
    #pragma unroll
    for (int off = 32; off > 0; off >>= 1) {
        dot  += __shfl_down(dot,  off, 64);
        rsum += __shfl_down(rsum, off, 64);
    }

    if (lane == 0) {
        float xi  = ((const float*)xs)[row];
        float aii = adj[(size_t)row * N_CITIES + row];
        float y   = (aii + 2.0f * rsum) * xi - dot;
        out[row]  = (y > 0.0f) ? 1.0f : ((y < 0.0f) ? -1.0f : 0.0f);
    }
}

extern "C" void kernel_launch(void* const* d_in, const int* in_sizes, int n_in,
                              void* d_out, int out_size, void* d_ws, size_t ws_size,
                              hipStream_t stream) {
    const float* adj = (const float*)d_in[0];
    const float* x   = (const float*)d_in[1];
    float* out       = (float*)d_out;

    const int grid = N_CITIES / ROWS_PER_BLOCK;   // 1024 blocks
    hopfield_onestep_kernel<<<grid, THREADS, 0, stream>>>(adj, x, out);
}